// Round 7
// baseline (287.589 us; speedup 1.0000x reference)
//
#include <hip/hip_runtime.h>
#include <hip/hip_bf16.h>
#include <math.h>

// Problem constants
#define NCLS   19
#define KPC    100
#define NA     1900       // anchors (also first NA contrast cols)
#define NM     20000      // memory rows
#define NC     21900      // contrast rows = NA + NM
#define NCP2   22016      // contrast cols padded to multiple of 128
#define D      256        // feature dim
#define HW     16384      // 128*128
#define NPIX   131072     // 8*128*128

typedef __attribute__((ext_vector_type(8))) short bf16x8;
typedef __attribute__((ext_vector_type(4))) float f32x4;

// workspace byte offsets
#define WS_ROWS  7680      // 1920 f
#define WS_ROWP  15360     // 1920 f
#define WS_HIST  23040     // 19 ints
#define WS_CLAB  23296     // 22016 ints
#define WS_CT2   111616    // bf16 [32 kq][22016 n][8] = 11,272,192 B

__device__ __forceinline__ short f2bf(float x) {
    __hip_bfloat16 h = __float2bfloat16(x);
    return *(short*)&h;
}

// ---------------- K1: sampler + anchor gather/normalize fused ----------------
// Block c: find first 100 pixels of class c (ascending), then gather+normalize
// those anchors into Ct2 cols c*100..c*100+99.
__global__ void sample_gather_kernel(const int* __restrict__ labels,
                                     const float* __restrict__ pixel,
                                     short* __restrict__ Ct2) {
    const int c = blockIdx.x;
    const int t = threadIdx.x;
    const int wave = t >> 6, lane = t & 63;
    __shared__ int s_idx[KPC];
    __shared__ int s_base;
    __shared__ int s_wavecnt[4];
    if (t == 0) s_base = 0;
    __syncthreads();
    for (int start = 0; start < NPIX; start += 256) {
        const int i = start + t;
        const bool pred = (labels[i] == c);
        const unsigned long long b = __ballot(pred);
        if (lane == 0) s_wavecnt[wave] = __popcll(b);
        __syncthreads();
        const int base = s_base;
        int wbase = 0;
        for (int w = 0; w < wave; ++w) wbase += s_wavecnt[w];
        const int chunk_total = s_wavecnt[0] + s_wavecnt[1] + s_wavecnt[2] + s_wavecnt[3];
        if (pred) {
            const int rank = base + wbase + __popcll(b & ((1ULL << lane) - 1ULL));
            if (rank < KPC) s_idx[rank] = i;
        }
        __syncthreads();
        if (t == 0) s_base = base + chunk_total;
        if (base + chunk_total >= KPC) break;
    }
    __syncthreads();
    // phase 2: gather + normalize (8 anchor slots x 32 threads)
    const int slot = t >> 5, kq = t & 31;
    for (int r = slot; r < KPC; r += 8) {
        const int p = s_idx[r];
        const int b = p >> 14;
        const int hw = p & (HW - 1);
        const float* base = pixel + ((size_t)(b * D + kq * 8)) * HW + hw;
        float v[8];
        float ssq = 0.f;
        #pragma unroll
        for (int j = 0; j < 8; ++j) { v[j] = base[(size_t)j * HW]; ssq += v[j] * v[j]; }
        #pragma unroll
        for (int o = 16; o; o >>= 1) ssq += __shfl_xor(ssq, o, 32);
        const float inv = 1.0f / fmaxf(sqrtf(ssq), 1e-12f);
        bf16x8 outv;
        #pragma unroll
        for (int j = 0; j < 8; ++j) outv[j] = f2bf(v[j] * inv);
        *(bf16x8*)(Ct2 + ((size_t)kq * NCP2 + c * KPC + r) * 8) = outv;
    }
}

// ---------------- K2: memory normalize + labels + zeros + histogram ----------------
__global__ void prep_kernel(const float* __restrict__ mem, const int* __restrict__ memlab,
                            float* rowS, float* rowP, int* clab, int* hist,
                            short* __restrict__ Ct2) {
    const int b = blockIdx.x, t = threadIdx.x;
    if (b < 2500) {                       // normalize memory rows -> Ct2 cols NA..NC
        const int r = b * 8 + (t >> 5);
        const int kq = t & 31;
        const float4 v0 = *(const float4*)(mem + (size_t)r * D + kq * 8);
        const float4 v1 = *(const float4*)(mem + (size_t)r * D + kq * 8 + 4);
        float ssq = v0.x*v0.x + v0.y*v0.y + v0.z*v0.z + v0.w*v0.w
                  + v1.x*v1.x + v1.y*v1.y + v1.z*v1.z + v1.w*v1.w;
        #pragma unroll
        for (int o = 16; o; o >>= 1) ssq += __shfl_xor(ssq, o, 32);
        const float inv = 1.0f / fmaxf(sqrtf(ssq), 1e-12f);
        bf16x8 outv;
        outv[0] = f2bf(v0.x * inv); outv[1] = f2bf(v0.y * inv);
        outv[2] = f2bf(v0.z * inv); outv[3] = f2bf(v0.w * inv);
        outv[4] = f2bf(v1.x * inv); outv[5] = f2bf(v1.y * inv);
        outv[6] = f2bf(v1.z * inv); outv[7] = f2bf(v1.w * inv);
        *(bf16x8*)(Ct2 + ((size_t)kq * NCP2 + NA + r) * 8) = outv;
    } else if (b < 2586) {                // labels + zero accumulators + zero pad cols
        const int i = (b - 2500) * 256 + t;     // 0..22015
        clab[i] = (i < NA) ? ((i * 5243) >> 19)
                           : ((i < NC) ? memlab[i - NA] : -1);
        if (i < 1920) { rowS[i] = 0.f; rowP[i] = 0.f; }
        if (i < 32 * (NCP2 - NC)) {
            const int kq = i / (NCP2 - NC);
            const int n  = NC + (i - kq * (NCP2 - NC));
            bf16x8 z = {};
            *(bf16x8*)(Ct2 + ((size_t)kq * NCP2 + n) * 8) = z;
        }
    } else {                              // b==2586: class histogram
        __shared__ int h[NCLS];
        if (t < NCLS) h[t] = 0;
        __syncthreads();
        for (int i = t; i < NM; i += 256) atomicAdd(&h[memlab[i]], 1);
        __syncthreads();
        if (t < NCLS) hist[t] = h[t];
    }
}

// ---------------- K3: MFMA GEMM, anchors-in-registers, T=2 tiles/block ----------------
// Anchor (m) operand: full-K in 128 VGPRs, loaded once per block, reused across
// 2 n-tiles. Only contrast (n) chunks stage through 16KB LDS -> per-barrier
// drain halves vs R6 and B-bytes never restaged. No device fences (separate
// finalize kernel). Grid: 8 XCDs x 165; n-groups partitioned per XCD for L2.
__global__ __launch_bounds__(256, 2)
void gemm_kernel(const short* __restrict__ Ct2, const int* __restrict__ clab,
                 float* __restrict__ rowS, float* __restrict__ rowP) {
    __shared__ __align__(16) short As[8 * 128 * 8];   // contrast chunk, 16 KB
    const int tid  = threadIdx.x;
    const int lane = tid & 63;
    const int w    = tid >> 6;
    const int wn   = w >> 1, wm = w & 1;
    const int quad = lane >> 4, l16 = lane & 15;

    const int L   = blockIdx.x;
    const int xcd = L & 7;
    const int j   = L >> 3;               // 0..164
    const int m_t = j % 15;
    const int gl  = j / 15;               // 0..10
    const int gcnt = (xcd < 6) ? 11 : 10;
    if (gl >= gcnt) return;               // 30 idle blocks
    const int g   = (xcd < 6) ? xcd * 11 + gl : 66 + (xcd - 6) * 10 + gl;  // 0..85
    const int m0  = m_t * 128;

    // ---- preload anchor fragments: full K, 32 x 16B coalesced, once ----
    bf16x8 Bfr[8][4];
    {
        const int mb = m0 + wm * 64 + l16;
        #pragma unroll
        for (int q = 0; q < 8; ++q)
            #pragma unroll
            for (int mi = 0; mi < 4; ++mi)
                Bfr[q][mi] = *(const bf16x8*)(Ct2 + ((size_t)(q * 4 + quad) * NCP2 + mb + mi * 16) * 8);
    }

    for (int t2 = 0; t2 < 2; ++t2) {
        const int n0 = g * 256 + t2 * 128;
        f32x4 acc[4][4] = {};             // [mi][ni]

        for (int kc = 0; kc < 4; ++kc) {
            #pragma unroll
            for (int i = 0; i < 4; ++i) {
                const int cc   = w * 4 + i;        // 0..15
                const int kql  = cc >> 1;          // 0..7
                const int half = (cc & 1) * 64;
                __builtin_amdgcn_global_load_lds(
                    (const __attribute__((address_space(1))) void*)(Ct2 + ((size_t)(kc * 8 + kql) * NCP2 + n0 + half + lane) * 8),
                    (__attribute__((address_space(3))) void*)(As + (size_t)(kql * 128 + half + lane) * 8),
                    16, 0, 0);
            }
            __syncthreads();
            #pragma unroll
            for (int ks = 0; ks < 2; ++ks) {
                bf16x8 af[4];
                #pragma unroll
                for (int ni = 0; ni < 4; ++ni)
                    af[ni] = *(const bf16x8*)(As + (size_t)((ks * 4 + quad) * 128 + wn * 64 + ni * 16 + l16) * 8);
                #pragma unroll
                for (int mi = 0; mi < 4; ++mi)
                    #pragma unroll
                    for (int ni = 0; ni < 4; ++ni)
                        acc[mi][ni] = __builtin_amdgcn_mfma_f32_16x16x32_bf16(
                            af[ni], Bfr[kc * 2 + ks][mi], acc[mi][ni], 0, 0, 0);
            }
            __syncthreads();
        }

        // in-lane epilogue: n = n0+wn*64+ni*16+quad*4+r (row), m = col (l16)
        const int nbase = n0 + wn * 64 + quad * 4;
        int labv[16];
        #pragma unroll
        for (int ni = 0; ni < 4; ++ni)
            #pragma unroll
            for (int r = 0; r < 4; ++r)
                labv[ni * 4 + r] = clab[nbase + ni * 16 + r];
        #pragma unroll
        for (int mi = 0; mi < 4; ++mi) {
            const int m    = m0 + wm * 64 + mi * 16 + l16;
            const int mlab = (m * 5243) >> 19;     // m/100; >=19 for pad rows
            float s = 0.f, p = 0.f;
            #pragma unroll
            for (int ni = 0; ni < 4; ++ni)
                #pragma unroll
                for (int r = 0; r < 4; ++r) {
                    const int n  = nbase + ni * 16 + r;
                    const int lv = labv[ni * 4 + r];
                    const float l = acc[mi][ni][r] * 10.0f;
                    if (lv >= 0 && n != m) {       // lv<0 masks tail pad cols
                        s += __expf(l);
                        if (lv == mlab) p += l;
                    }
                }
            s += __shfl_xor(s, 16, 64); s += __shfl_xor(s, 32, 64);
            p += __shfl_xor(p, 16, 64); p += __shfl_xor(p, 32, 64);
            if (quad == 0 && m < NA) {
                atomicAdd(&rowS[m], s);
                atomicAdd(&rowP[m], p);
            }
        }
    }
}

// ---------------- K4: final loss ----------------
__global__ void finalize_kernel(const float* __restrict__ rowS, const float* __restrict__ rowP,
                                const int* __restrict__ hist, float* __restrict__ out) {
    const int t = threadIdx.x;
    float sum = 0.f;
    for (int n = t; n < NA; n += 256) {
        const int cls = (n * 5243) >> 19;
        const float cnt = 99.0f + (float)hist[cls];
        const float logS = logf(rowS[n] + 1e-12f);
        sum += (rowP[n] - cnt * logS) / cnt;
    }
    #pragma unroll
    for (int o = 32; o; o >>= 1) sum += __shfl_xor(sum, o, 64);
    __shared__ float rs[4];
    if ((t & 63) == 0) rs[t >> 6] = sum;
    __syncthreads();
    if (t == 0)
        out[0] = -(10.0f / 7.0f) * ((rs[0] + rs[1] + rs[2] + rs[3]) / 1900.0f);
}

extern "C" void kernel_launch(void* const* d_in, const int* in_sizes, int n_in,
                              void* d_out, int out_size, void* d_ws, size_t ws_size,
                              hipStream_t stream) {
    const float* pixel  = (const float*)d_in[0];   // [8,256,128,128]
    const int*   labels = (const int*)d_in[1];     // [8,128,128]
    const float* mem    = (const float*)d_in[2];   // [20000,256]
    const int*   memlab = (const int*)d_in[3];     // [20000]
    char* ws = (char*)d_ws;
    float* rowS = (float*)(ws + WS_ROWS);
    float* rowP = (float*)(ws + WS_ROWP);
    int*   hist = (int*)(ws + WS_HIST);
    int*   clab = (int*)(ws + WS_CLAB);
    short* Ct2  = (short*)(ws + WS_CT2);
    float* out  = (float*)d_out;

    sample_gather_kernel<<<dim3(NCLS), dim3(256), 0, stream>>>(labels, pixel, Ct2);
    prep_kernel<<<dim3(2587), dim3(256), 0, stream>>>(mem, memlab, rowS, rowP, clab, hist, Ct2);
    gemm_kernel<<<dim3(1320), dim3(256), 0, stream>>>(Ct2, clab, rowS, rowP);
    finalize_kernel<<<dim3(1), dim3(256), 0, stream>>>(rowS, rowP, hist, out);
}